// Round 3
// baseline (57945.599 us; speedup 1.0000x reference)
//
#include <hip/hip_runtime.h>
#include <hip/hip_cooperative_groups.h>
#include <math.h>

namespace cg = cooperative_groups;

#define BATCH 512
#define SEQ   200
#define DIN   64
#define HID   512
#define GW    2048   // 4*HID
#define EPS   1e-5f
#define PW    32     // weight panel width (n cols per block)
#define NBLK  256
#define NTHR  512
#define SMEM_BYTES (65536 + 16384 + 128)   // weight panel (hi+lo) | GS | red

typedef _Float16 half_t;
typedef half_t half8 __attribute__((ext_vector_type(8)));
typedef float  f32x4  __attribute__((ext_vector_type(4)));
typedef float  f32x16 __attribute__((ext_vector_type(16)));

struct Params {
  const float *x, *g1, *b1;
  const float *W0, *W1, *W2, *W3;   // ih0, hh0, ih1, hh1  (2048, K) row-major
  const float *b_ih0,*b_hh0,*b_ih1,*b_hh1;
  const float *g_ih0,*be_ih0,*g_hh0,*be_hh0,*g_ho0,*be_ho0;
  const float *g_ih1,*be_ih1,*g_hh1,*be_hh1,*g_ho1,*be_ho1;
  float *G;                         // [4][BATCH][GW]
  float *h0,*c0,*h1,*c1;
  half_t *h0h,*h0l,*h1h,*h1l;
  half_t *xh,*xl;                   // [SEQ][BATCH][DIN] ln1(x) fp16 hi/lo
  float *mu,*rs;
};

__device__ __forceinline__ float sigf(float x){ return 1.0f/(1.0f+expf(-x)); }

// 512-thread block reduce of 4 values; red = float[32] shared
__device__ __forceinline__ void bred4(float&a,float&b,float&c,float&d,float* red){
  #pragma unroll
  for(int o=32;o;o>>=1){
    a+=__shfl_down(a,o); b+=__shfl_down(b,o);
    c+=__shfl_down(c,o); d+=__shfl_down(d,o);
  }
  const int lane = threadIdx.x & 63, wid = threadIdx.x >> 6;
  if(lane==0){ red[wid*4+0]=a; red[wid*4+1]=b; red[wid*4+2]=c; red[wid*4+3]=d; }
  __syncthreads();
  float ta=0,tb=0,tc=0,td=0;
  #pragma unroll
  for (int q=0;q<8;q++){ ta+=red[q*4+0]; tb+=red[q*4+1]; tc+=red[q*4+2]; td+=red[q*4+3]; }
  a=ta; b=tb; c=tc; d=td;
  __syncthreads();
}

struct Afrag { half8 h00,h01,h10,h11,l00,l01,l10,l11; };
struct Bfrag { half8 h0,h1,l0,l1; };

__device__ __forceinline__ Afrag loadA(const half_t*A0h,const half_t*A0l,
                                       const half_t*A1h,const half_t*A1l,int off){
  Afrag f;
  f.h00 = *(const half8*)(A0h+off);  f.h01 = *(const half8*)(A0h+off+16);
  f.h10 = *(const half8*)(A1h+off);  f.h11 = *(const half8*)(A1h+off+16);
  f.l00 = *(const half8*)(A0l+off);  f.l01 = *(const half8*)(A0l+off+16);
  f.l10 = *(const half8*)(A1l+off);  f.l11 = *(const half8*)(A1l+off+16);
  return f;
}

__device__ __forceinline__ Bfrag loadB(const half_t* WpH, const half_t* WpL,
                                       int c, int lane){
  Bfrag f;
  const half_t* b0 = WpH + (size_t)c*1024 + lane*8;
  const half_t* l0 = WpL + (size_t)c*1024 + lane*8;
  f.h0 = *(const half8*)(b0);  f.h1 = *(const half8*)(b0+512);
  f.l0 = *(const half8*)(l0);  f.l1 = *(const half8*)(l0+512);
  return f;
}

#define MMSTEP(A,B) do { \
  acc0 = __builtin_amdgcn_mfma_f32_32x32x16_f16(A.h00, B.h0, acc0, 0,0,0); \
  acc1 = __builtin_amdgcn_mfma_f32_32x32x16_f16(A.h10, B.h0, acc1, 0,0,0); \
  acc0 = __builtin_amdgcn_mfma_f32_32x32x16_f16(A.l00, B.h0, acc0, 0,0,0); \
  acc1 = __builtin_amdgcn_mfma_f32_32x32x16_f16(A.l10, B.h0, acc1, 0,0,0); \
  acc0 = __builtin_amdgcn_mfma_f32_32x32x16_f16(A.h00, B.l0, acc0, 0,0,0); \
  acc1 = __builtin_amdgcn_mfma_f32_32x32x16_f16(A.h10, B.l0, acc1, 0,0,0); \
  acc0 = __builtin_amdgcn_mfma_f32_32x32x16_f16(A.h01, B.h1, acc0, 0,0,0); \
  acc1 = __builtin_amdgcn_mfma_f32_32x32x16_f16(A.h11, B.h1, acc1, 0,0,0); \
  acc0 = __builtin_amdgcn_mfma_f32_32x32x16_f16(A.l01, B.h1, acc0, 0,0,0); \
  acc1 = __builtin_amdgcn_mfma_f32_32x32x16_f16(A.l11, B.h1, acc1, 0,0,0); \
  acc0 = __builtin_amdgcn_mfma_f32_32x32x16_f16(A.h01, B.l1, acc0, 0,0,0); \
  acc1 = __builtin_amdgcn_mfma_f32_32x32x16_f16(A.h11, B.l1, acc1, 0,0,0); \
} while(0)

__device__ __forceinline__ void update_unit(const Params& P, int layer, int b,
                                            float* GS, float* red){
  const float *GA,*GB,*bA,*bB,*gA,*beA,*gB,*beB,*gH,*bH;
  float *cs,*hs; half_t *hhx,*hlx;
  const size_t rb = (size_t)b*GW;
  if (layer==0){
    GA = P.G + rb;                      GB = P.G + (size_t)BATCH*GW + rb;
    bA=P.b_ih0; bB=P.b_hh0;
    gA=P.g_ih0; beA=P.be_ih0; gB=P.g_hh0; beB=P.be_hh0; gH=P.g_ho0; bH=P.be_ho0;
    cs=P.c0+b*HID; hs=P.h0+b*HID; hhx=P.h0h+b*HID; hlx=P.h0l+b*HID;
  } else {
    GA = P.G + 2*(size_t)BATCH*GW + rb; GB = P.G + 3*(size_t)BATCH*GW + rb;
    bA=P.b_ih1; bB=P.b_hh1;
    gA=P.g_ih1; beA=P.be_ih1; gB=P.g_hh1; beB=P.be_hh1; gH=P.g_ho1; bH=P.be_ho1;
    cs=P.c1+b*HID; hs=P.h1+b*HID; hhx=P.h1h+b*HID; hlx=P.h1l+b*HID;
  }
  const int tid = threadIdx.x;

  // pass1: bias-add, stage to LDS, LN stats (one f32x4 per thread per vector)
  float sa=0,ssa=0,sb=0,ssb=0;
  {
    const int i = tid*4;
    f32x4 va = *(const f32x4*)(GA+i);  va += *(const f32x4*)(bA+i);
    *(f32x4*)(GS+i) = va;
    f32x4 vb = *(const f32x4*)(GB+i);  vb += *(const f32x4*)(bB+i);
    *(f32x4*)(GS+GW+i) = vb;
    #pragma unroll
    for (int q=0;q<4;q++){ sa+=va[q]; ssa+=va[q]*va[q]; sb+=vb[q]; ssb+=vb[q]*vb[q]; }
  }
  bred4(sa,ssa,sb,ssb,red);
  const float ma = sa*(1.0f/GW);
  const float ra = rsqrtf(ssa*(1.0f/GW) - ma*ma + EPS);
  const float mb = sb*(1.0f/GW);
  const float rb_ = rsqrtf(ssb*(1.0f/GW) - mb*mb + EPS);

  // pass2: one gate element per thread (j = tid)
  const int j = tid;
  float iv = ((GS[j      ]-ma)*ra*gA[j      ]+beA[j      ]) + ((GS[GW+j      ]-mb)*rb_*gB[j      ]+beB[j      ]);
  float fv = ((GS[j+  HID]-ma)*ra*gA[j+  HID]+beA[j+  HID]) + ((GS[GW+j+  HID]-mb)*rb_*gB[j+  HID]+beB[j+  HID]);
  float gv = ((GS[j+2*HID]-ma)*ra*gA[j+2*HID]+beA[j+2*HID]) + ((GS[GW+j+2*HID]-mb)*rb_*gB[j+2*HID]+beB[j+2*HID]);
  float ov = ((GS[j+3*HID]-ma)*ra*gA[j+3*HID]+beA[j+3*HID]) + ((GS[GW+j+3*HID]-mb)*rb_*gB[j+3*HID]+beB[j+3*HID]);
  float cn = sigf(fv)*cs[j] + sigf(iv)*tanhf(gv);
  cs[j] = cn;
  float u = tanhf(cn);
  float o = sigf(ov);
  float s_u = u, s_uu = u*u, d0=0, d1=0;
  bred4(s_u,s_uu,d0,d1,red);
  const float mu_u = s_u*(1.0f/HID);
  const float ru   = rsqrtf(s_uu*(1.0f/HID) - mu_u*mu_u + EPS);

  // pass3: h = sigmoid(o) * LN(tanh(c)); fp32 + fp16 hi/lo split (u,o are thread-local)
  float v = o * ((u-mu_u)*ru*gH[j] + bH[j]);
  hs[j] = v;
  half_t hv = (half_t)v;
  hhx[j] = hv;
  hlx[j] = (half_t)(v - (float)hv);
}

__global__ __launch_bounds__(NTHR, 1) void persist(Params P)
{
  extern __shared__ char smem[];
  half_t* WpH = (half_t*)smem;                 // fragment-major panel, hi plane
  float*  GS  = (float*)(smem + 65536);        // 2*GW staging for update
  float*  red = GS + 2*GW;                     // 32 floats

  cg::grid_group grid = cg::this_grid();

  const int blk = blockIdx.x;       // 0..255
  const int r   = blk >> 6;         // region: 0=ih0, 1=hh0, 2=ih1, 3=hh1
  const int p   = blk & 63;         // panel (32 cols)
  const int tid = threadIdx.x;
  const int Kd  = (r==0) ? DIN : HID;
  half_t* WpL = WpH + PW*Kd;        // lo plane

  // ---- phase 0a: weight panel -> LDS, fragment-major fp16 hi/lo ----
  {
    const float* Wsrc = (r==0)?P.W0:((r==1)?P.W1:((r==2)?P.W2:P.W3));
    for (int idx = tid; idx < PW*Kd; idx += NTHR){
      int j = idx & 7, l = (idx>>3)&63, s = idx>>9;
      int n = p*PW + (l&31);
      int k = s*16 + ((l>>5)<<3) + j;
      float v = Wsrc[(size_t)n*Kd + k];
      half_t h = (half_t)v;
      WpH[idx] = h;
      WpL[idx] = (half_t)(v - (float)h);
    }
  }
  // ---- phase 0a': ln1 stats (rows blk, blk+256) ----
  for (int rr=0; rr<2; rr++){
    int b = blk + rr*NBLK;
    const float* xb = P.x + (size_t)b*SEQ*DIN;
    float s=0, ss=0, d0=0, d1=0;
    for (int i=tid;i<SEQ*DIN;i+=NTHR){ float v=xb[i]; s+=v; ss+=v*v; }
    bred4(s,ss,d0,d1,red);
    if (tid==0){
      float m = s*(1.0f/(SEQ*DIN));
      P.mu[b] = m;
      P.rs[b] = rsqrtf(ss*(1.0f/(SEQ*DIN)) - m*m + EPS);
    }
  }
  __threadfence();
  grid.sync();
  __threadfence();
  // ---- phase 0b: xsplit = ln1(x) as fp16 hi/lo, [t][b][k] ----
  {
    const size_t total = (size_t)SEQ*BATCH*DIN;
    for (size_t i = (size_t)blk*NTHR + tid; i < total; i += (size_t)NBLK*NTHR){
      int k = (int)(i & 63);
      int b = (int)((i>>6) & 511);
      int t = (int)(i>>15);
      float v = (P.x[((size_t)b*SEQ + t)*DIN + k] - P.mu[b]) * P.rs[b]
                * P.g1[t*DIN+k] + P.b1[t*DIN+k];
      half_t h = (half_t)v;
      P.xh[i] = h;
      P.xl[i] = (half_t)(v - (float)h);
    }
  }
  __threadfence();
  grid.sync();
  __threadfence();

  // ---- per-wave geometry for mm ----
  const int w    = tid >> 6;          // 0..7, wave m-origin = w*64
  const int lane = tid & 63;
  const int ln31 = lane & 31;
  const int lk8  = (lane >> 5) << 3;
  const int wm0  = w * 64;
  const int row0 = wm0 + ln31;
  const int row1 = wm0 + 32 + ln31;
  const int C    = Kd >> 5;           // 32-k chunks: 2 or 16

  const half_t *HB_h, *HB_l;          // h-state split base for r>=1
  if (r==3){ HB_h = P.h1h; HB_l = P.h1l; }
  else     { HB_h = P.h0h; HB_l = P.h0l; }

  float* Gr = P.G + (size_t)r*BATCH*GW + p*PW;

  // ---- tick loop ----
  for (int t = 0; t <= SEQ; ++t){
    const bool mmact = (r<=1) ? (t < SEQ) : (t >= 1);
    if (mmact){
      const half_t *A0h,*A0l,*A1h,*A1l;
      if (r==0){
        const half_t* bx = P.xh + (size_t)t*BATCH*DIN;
        const half_t* bl = P.xl + (size_t)t*BATCH*DIN;
        A0h = bx + (size_t)row0*DIN + lk8;  A0l = bl + (size_t)row0*DIN + lk8;
        A1h = bx + (size_t)row1*DIN + lk8;  A1l = bl + (size_t)row1*DIN + lk8;
      } else {
        A0h = HB_h + (size_t)row0*HID + lk8; A0l = HB_l + (size_t)row0*HID + lk8;
        A1h = HB_h + (size_t)row1*HID + lk8; A1l = HB_l + (size_t)row1*HID + lk8;
      }
      f32x16 acc0 = {0.f,0.f,0.f,0.f,0.f,0.f,0.f,0.f,0.f,0.f,0.f,0.f,0.f,0.f,0.f,0.f};
      f32x16 acc1 = acc0;

      Afrag Aa = loadA(A0h,A0l,A1h,A1l, 0);
      for (int c=0; c<C; c+=2){
        Afrag Ab = loadA(A0h,A0l,A1h,A1l, (c+1)*32);
        Bfrag Ba = loadB(WpH,WpL,c,lane);
        MMSTEP(Aa,Ba);
        if (c+2 < C) Aa = loadA(A0h,A0l,A1h,A1l, (c+2)*32);
        Bfrag Bb = loadB(WpH,WpL,c+1,lane);
        MMSTEP(Ab,Bb);
      }

      // C/D 32x32: col = lane&31, row = (reg&3)+8*(reg>>2)+4*(lane>>5)
      const int rbase = (lane>>5)<<2;
      #pragma unroll
      for (int reg=0; reg<16; reg++){
        const int m = wm0 + (reg&3) + ((reg>>2)<<3) + rbase;
        __builtin_nontemporal_store(acc0[reg], &Gr[(size_t)m*GW + ln31]);
        __builtin_nontemporal_store(acc1[reg], &Gr[(size_t)(m+32)*GW + ln31]);
      }
    }
    __threadfence();
    grid.sync();
    __threadfence();

    // update: units blk, blk+256 (layer0), blk+512, blk+768 (layer1)
    #pragma unroll
    for (int u=0; u<4; u++){
      const int unit  = blk + u*NBLK;
      const int layer = unit >> 9;
      const int b     = unit & 511;
      const bool act  = (layer==0) ? (t < SEQ) : (t >= 1);
      if (act) update_unit(P, layer, b, GS, red);
    }
    __threadfence();
    grid.sync();
    __threadfence();
  }
}

// Dense head: 512 -> 128 -> 64 -> 32 -> 1, one block per batch row
__global__ __launch_bounds__(256) void head_kernel(
    const float* __restrict__ h1,
    const float* __restrict__ Wd1, const float* __restrict__ bd1,
    const float* __restrict__ Wd2, const float* __restrict__ bd2,
    const float* __restrict__ Wd3, const float* __restrict__ bd3,
    const float* __restrict__ Wd4, const float* __restrict__ bd4,
    float* __restrict__ out)
{
  const int b = blockIdx.x;
  __shared__ float hv[HID];
  __shared__ float z1[128];
  __shared__ float z2[64];
  __shared__ float z3[32];
  const int tid = threadIdx.x;
  for (int i=tid;i<HID;i+=256) hv[i]=h1[(size_t)b*HID+i];
  __syncthreads();
  if (tid<128){
    float acc=bd1[tid]; const float* w=Wd1+(size_t)tid*512;
    for(int k=0;k<512;k++) acc+=hv[k]*w[k];
    z1[tid]=fmaxf(acc,0.f);
  }
  __syncthreads();
  if (tid<64){
    float acc=bd2[tid]; const float* w=Wd2+(size_t)tid*128;
    for(int k=0;k<128;k++) acc+=z1[k]*w[k];
    z2[tid]=fmaxf(acc,0.f);
  }
  __syncthreads();
  if (tid<32){
    float acc=bd3[tid]; const float* w=Wd3+(size_t)tid*64;
    for(int k=0;k<64;k++) acc+=z2[k]*w[k];
    z3[tid]=fmaxf(acc,0.f);
  }
  __syncthreads();
  if (tid==0){
    float acc=bd4[0];
    for(int k=0;k<32;k++) acc+=z3[k]*Wd4[k];
    out[b]=acc;
  }
}

extern "C" void kernel_launch(void* const* d_in, const int* in_sizes, int n_in,
                              void* d_out, int out_size, void* d_ws, size_t ws_size,
                              hipStream_t stream) {
  const float* x      = (const float*)d_in[0];
  const float* ln1_g  = (const float*)d_in[1];
  const float* ln1_b  = (const float*)d_in[2];
  const float* W_ih0  = (const float*)d_in[3];
  const float* b_ih0  = (const float*)d_in[4];
  const float* W_hh0  = (const float*)d_in[5];
  const float* b_hh0  = (const float*)d_in[6];
  const float* g_ih0  = (const float*)d_in[7];
  const float* be_ih0 = (const float*)d_in[8];
  const float* g_hh0  = (const float*)d_in[9];
  const float* be_hh0 = (const float*)d_in[10];
  const float* g_ho0  = (const float*)d_in[11];
  const float* be_ho0 = (const float*)d_in[12];
  const float* W_ih1  = (const float*)d_in[13];
  const float* b_ih1  = (const float*)d_in[14];
  const float* W_hh1  = (const float*)d_in[15];
  const float* b_hh1  = (const float*)d_in[16];
  const float* g_ih1  = (const float*)d_in[17];
  const float* be_ih1 = (const float*)d_in[18];
  const float* g_hh1  = (const float*)d_in[19];
  const float* be_hh1 = (const float*)d_in[20];
  const float* g_ho1  = (const float*)d_in[21];
  const float* be_ho1 = (const float*)d_in[22];
  const float* Wd1    = (const float*)d_in[23];
  const float* bd1    = (const float*)d_in[24];
  const float* Wd2    = (const float*)d_in[25];
  const float* bd2    = (const float*)d_in[26];
  const float* Wd3    = (const float*)d_in[27];
  const float* bd3    = (const float*)d_in[28];
  const float* Wd4    = (const float*)d_in[29];
  const float* bd4    = (const float*)d_in[30];
  float* out = (float*)d_out;

  // ---- workspace layout ----
  float* ws = (float*)d_ws;
  float* G  = ws;                                   // 4*512*2048 f32 = 16 MB
  float* h0 = G  + 4*(size_t)BATCH*GW;              // fp32 state block (zeroed)
  float* c0 = h0 + (size_t)BATCH*HID;
  float* h1 = c0 + (size_t)BATCH*HID;
  float* c1 = h1 + (size_t)BATCH*HID;
  half_t* h0h = (half_t*)(c1 + (size_t)BATCH*HID);  // fp16 state splits (zeroed)
  half_t* h0l = h0h + (size_t)BATCH*HID;
  half_t* h1h = h0l + (size_t)BATCH*HID;
  half_t* h1l = h1h + (size_t)BATCH*HID;
  half_t* xh  = h1l + (size_t)BATCH*HID;            // 200*512*64 halves
  half_t* xl  = xh + (size_t)SEQ*BATCH*DIN;
  float* mu = (float*)(xl + (size_t)SEQ*BATCH*DIN); // 512
  float* rs = mu + BATCH;                           // 512

  // zero h0,c0,h1,c1 (fp32) + h0h,h0l,h1h,h1l (fp16) in one contiguous memset
  hipMemsetAsync(h0, 0, 4*(size_t)BATCH*HID*4 + 4*(size_t)BATCH*HID*2, stream);

  static int attr_done = 0;
  if (!attr_done){
    (void)hipFuncSetAttribute((const void*)persist,
        hipFuncAttributeMaxDynamicSharedMemorySize, SMEM_BYTES);
    attr_done = 1;
  }

  Params Pp;
  Pp.x=x; Pp.g1=ln1_g; Pp.b1=ln1_b;
  Pp.W0=W_ih0; Pp.W1=W_hh0; Pp.W2=W_ih1; Pp.W3=W_hh1;
  Pp.b_ih0=b_ih0; Pp.b_hh0=b_hh0; Pp.b_ih1=b_ih1; Pp.b_hh1=b_hh1;
  Pp.g_ih0=g_ih0; Pp.be_ih0=be_ih0; Pp.g_hh0=g_hh0; Pp.be_hh0=be_hh0;
  Pp.g_ho0=g_ho0; Pp.be_ho0=be_ho0;
  Pp.g_ih1=g_ih1; Pp.be_ih1=be_ih1; Pp.g_hh1=g_hh1; Pp.be_hh1=be_hh1;
  Pp.g_ho1=g_ho1; Pp.be_ho1=be_ho1;
  Pp.G=G; Pp.h0=h0; Pp.c0=c0; Pp.h1=h1; Pp.c1=c1;
  Pp.h0h=h0h; Pp.h0l=h0l; Pp.h1h=h1h; Pp.h1l=h1l;
  Pp.xh=xh; Pp.xl=xl; Pp.mu=mu; Pp.rs=rs;

  void* kargs[] = { (void*)&Pp };
  hipLaunchCooperativeKernel((const void*)persist, dim3(NBLK), dim3(NTHR),
                             kargs, SMEM_BYTES, stream);

  head_kernel<<<BATCH, 256, 0, stream>>>(h1, Wd1, bd1, Wd2, bd2, Wd3, bd3, Wd4, bd4, out);
}

// Round 4
// 6027.667 us; speedup vs baseline: 9.6133x; 9.6133x over previous
//
#include <hip/hip_runtime.h>
#include <math.h>

#define BATCH 512
#define SEQ   200
#define DIN   64
#define HID   512
#define GW    2048   // 4*HID
#define EPS   1e-5f
#define NREG  4      // G regions: ih0 | hh0 | ih1 | hh1

typedef _Float16 half_t;
typedef half_t half8 __attribute__((ext_vector_type(8)));
typedef float  f32x4  __attribute__((ext_vector_type(4)));
typedef float  f32x16 __attribute__((ext_vector_type(16)));

#define WN0 (2048*64)     // W_ih0 elems
#define WN1 (2048*512)    // W_hh0 / W_ih1 / W_hh1 elems
#define WTOT (WN0 + 3*WN1)

__device__ __forceinline__ float sigf(float x){ return 1.0f/(1.0f+expf(-x)); }

// Reduce 4 values across a 256-thread block. red must be float[16] shared.
__device__ __forceinline__ void block_reduce4(float&a,float&b,float&c,float&d,float* red){
  #pragma unroll
  for(int o=32;o;o>>=1){
    a+=__shfl_down(a,o); b+=__shfl_down(b,o);
    c+=__shfl_down(c,o); d+=__shfl_down(d,o);
  }
  const int lane = threadIdx.x & 63, wid = threadIdx.x>>6;
  if(lane==0){ red[wid*4+0]=a; red[wid*4+1]=b; red[wid*4+2]=c; red[wid*4+3]=d; }
  __syncthreads();
  a = red[0]+red[4]+red[8]+red[12];
  b = red[1]+red[5]+red[9]+red[13];
  c = red[2]+red[6]+red[10]+red[14];
  d = red[3]+red[7]+red[11]+red[15];
  __syncthreads();
}

// Per-batch-row stats for ln1 (joint LayerNorm over (S,D) = 12800 elems)
__global__ __launch_bounds__(256) void ln1_stats(const float* __restrict__ x,
                                                 float* __restrict__ mu,
                                                 float* __restrict__ rs){
  const int b = blockIdx.x;
  const float* xb = x + (size_t)b*SEQ*DIN;
  float s=0, ss=0, d=0, e=0;
  for (int i=threadIdx.x; i<SEQ*DIN; i+=256){ float v=xb[i]; s+=v; ss+=v*v; }
  __shared__ float red[16];
  block_reduce4(s,ss,d,e,red);
  if (threadIdx.x==0){
    float m = s*(1.0f/(SEQ*DIN));
    mu[b] = m;
    rs[b] = rsqrtf(ss*(1.0f/(SEQ*DIN)) - m*m + EPS);
  }
}

// Split the 4 weight matrices into fp16 hi/lo in FRAGMENT-MAJOR packed layout.
// Packed index within a region (Kd = 64 or 512, C = Kd/32):
//   idx = ((p*C + c)*4 + nf*2 + ks)*512 + l*8 + j
//   n = p*64 + nf*32 + (l&31);  k = c*32 + ks*16 + (l>>5)*8 + j
// so a wave's B-fragment load is base + lane*16B: one fully-coalesced 1KB
// transaction, wave-uniform base.
__global__ __launch_bounds__(256) void wsplit(
    const float* __restrict__ W0, const float* __restrict__ W1,
    const float* __restrict__ W2, const float* __restrict__ W3,
    half_t* __restrict__ Wh, half_t* __restrict__ Wl)
{
  int i = blockIdx.x*256 + threadIdx.x;
  if (i >= WTOT) return;
  const float* src; int off, Kd;
  if (i < WN0){ src=W0; off=i; Kd=DIN; }
  else {
    int r = (i-WN0)/WN1; off = (i-WN0) - r*WN1; Kd=HID;
    src = (r==0)?W1:((r==1)?W2:W3);
  }
  const int C = Kd>>5;            // 2 or 16 (pow2)
  int j  = off & 7;
  int l  = (off>>3) & 63;
  int ks = (off>>9) & 1;
  int nf = (off>>10) & 1;
  int pc = off>>11;
  int c  = pc & (C-1);
  int p  = pc >> (Kd==DIN ? 1 : 4);
  int n  = p*64 + nf*32 + (l&31);
  int k  = c*32 + ks*16 + (l>>5)*8 + j;
  float v = src[(size_t)n*Kd + k];
  half_t h = (half_t)v;
  Wh[i] = h;
  Wl[i] = (half_t)(v - (float)h);
}

// One tick: gate pre-activation GEMMs via split-fp16 32x32x16 MFMA, layer-1 skewed.
// Both operands fragment-major & fully coalesced (A: h-state splits stored in
// fragment layout by tick_update; B: packed weights).
// grid.z = 4 regions: 0: G_ih0 = ln1(x[:,t,:]) @ W_ih0^T  (K=64, A in-register)
//                     1: G_hh0 = h0 @ W_hh0^T
//                     2: G_ih1 = h0 @ W_ih1^T
//                     3: G_hh1 = h1 @ W_hh1^T
// Bias added in tick_update. grid = (16,8,4), block = 256 (4 waves),
// wave tile 32m x 64n (one 32x32 acc pair).
__global__ __launch_bounds__(256) void tick_mm32(
    const float* __restrict__ x, const float* __restrict__ g1, const float* __restrict__ b1,
    const float* __restrict__ mu, const float* __restrict__ rsg,
    const half_t* __restrict__ h0fh, const half_t* __restrict__ h0fl,
    const half_t* __restrict__ h1fh, const half_t* __restrict__ h1fl,
    const half_t* __restrict__ Wh, const half_t* __restrict__ Wl,
    float* __restrict__ G, int t)
{
  const int z    = blockIdx.z;           // region 0..3
  const int tid  = threadIdx.x;
  const int lane = tid & 63;
  const int w    = tid >> 6;
  const int ln31 = lane & 31;
  const int lk8  = (lane >> 5) << 3;     // k sub-offset within a 16-chunk

  const int wm0 = blockIdx.y*64 + (w>>1)*32;   // wave m origin (32 rows)
  const int wn0 = blockIdx.x*128 + (w&1)*64;   // wave n origin (64 cols)
  const int p   = blockIdx.x*2 + (w&1);        // 64-col weight panel
  const int mch = wm0 >> 5;                    // 32-row m-chunk index

  const half_t* Bh = Wh + WN0; const half_t* Bl = Wl + WN0;
  const half_t* FAh = h0fh;    const half_t* FAl = h0fl;
  int Kd = HID;
  if (z==0){ Bh=Wh; Bl=Wl; Kd=DIN; }
  else if (z==2){ Bh=Wh+WN0+WN1; Bl=Wl+WN0+WN1; }
  else if (z==3){ FAh=h1fh; FAl=h1fl; Bh=Wh+WN0+2*WN1; Bl=Wl+WN0+2*WN1; }

  const int C32 = Kd >> 5;
  const int C16 = Kd >> 4;

  // wave-uniform bases (+ lane*8 elems = lane*16B)
  const half_t* Bph = Bh + (size_t)p*C32*2048 + lane*8;
  const half_t* Bpl = Bl + (size_t)p*C32*2048 + lane*8;
  const half_t* Aph = FAh + (size_t)mch*HID*32 + lane*8;  // mch*C16(=32)*512
  const half_t* Apl = FAl + (size_t)mch*HID*32 + lane*8;

  const int tq = (t < SEQ) ? t : (SEQ-1);   // t==200 layer0 result unused

  // z==0 A built in-register from ln1(x); per-lane row
  const int arow = wm0 + ln31;
  float m_=0.f, r_=0.f;
  const float *xr=nullptr, *gr=nullptr, *br=nullptr;
  if (z==0){
    m_ = mu[arow]; r_ = rsg[arow];
    xr = x  + (size_t)arow*(SEQ*DIN) + (size_t)tq*DIN + lk8;
    gr = g1 + (size_t)tq*DIN + lk8;
    br = b1 + (size_t)tq*DIN + lk8;
  }

  f32x16 acc0 = {0.f,0.f,0.f,0.f,0.f,0.f,0.f,0.f,0.f,0.f,0.f,0.f,0.f,0.f,0.f,0.f};
  f32x16 acc1 = acc0;

  struct Frag { half8 ah, al, bh0, bh1, bl0, bl1; };
  auto loadF = [&](int c16)->Frag{
    Frag f;
    if (z==0){
      const float* xp = xr + c16*16;
      const float* gp = gr + c16*16;
      const float* bp = br + c16*16;
      #pragma unroll
      for (int j=0;j<8;j++){
        float v = (xp[j]-m_)*r_*gp[j] + bp[j];
        half_t hv = (half_t)v;
        f.ah[j] = hv; f.al[j] = (half_t)(v - (float)hv);
      }
    } else {
      f.ah = *(const half8*)(Aph + (size_t)c16*512);
      f.al = *(const half8*)(Apl + (size_t)c16*512);
    }
    const size_t boff = (size_t)(c16>>1)*2048 + (size_t)(c16&1)*512;
    f.bh0 = *(const half8*)(Bph + boff);
    f.bh1 = *(const half8*)(Bph + boff + 1024);
    f.bl0 = *(const half8*)(Bpl + boff);
    f.bl1 = *(const half8*)(Bpl + boff + 1024);
    return f;
  };
  auto mmstep = [&](const Frag& f){
    acc0 = __builtin_amdgcn_mfma_f32_32x32x16_f16(f.ah, f.bh0, acc0, 0,0,0);
    acc1 = __builtin_amdgcn_mfma_f32_32x32x16_f16(f.ah, f.bh1, acc1, 0,0,0);
    acc0 = __builtin_amdgcn_mfma_f32_32x32x16_f16(f.al, f.bh0, acc0, 0,0,0);
    acc1 = __builtin_amdgcn_mfma_f32_32x32x16_f16(f.al, f.bh1, acc1, 0,0,0);
    acc0 = __builtin_amdgcn_mfma_f32_32x32x16_f16(f.ah, f.bl0, acc0, 0,0,0);
    acc1 = __builtin_amdgcn_mfma_f32_32x32x16_f16(f.ah, f.bl1, acc1, 0,0,0);
  };

  // 2-deep software pipeline over 16-k chunks (C16 is even: 4 or 32)
  Frag Fa = loadF(0);
  for (int c=0; c<C16; c+=2){
    Frag Fb = loadF(c+1);
    mmstep(Fa);
    if (c+2 < C16) Fa = loadF(c+2);
    mmstep(Fb);
  }

  // C/D 32x32: col = lane&31, row = (reg&3)+8*(reg>>2)+4*(lane>>5)
  // Nontemporal: G streams to L3/HBM; keeps per-XCD L2 for weights + h-state.
  float* Gr = G + (size_t)z*BATCH*GW + (size_t)0;
  const int rbase = (lane>>5)<<2;
  #pragma unroll
  for (int reg=0; reg<16; reg++){
    const int m = wm0 + (reg&3) + ((reg>>2)<<3) + rbase;
    __builtin_nontemporal_store(acc0[reg], &Gr[(size_t)m*GW + wn0 + ln31]);
    __builtin_nontemporal_store(acc1[reg], &Gr[(size_t)m*GW + wn0 + 32 + ln31]);
  }
}

// One block per (layer, batch-row): bias + gate LN + cell update + h LN.
// Emits h fp32 (linear) and fp16 hi/lo splits in MFMA-fragment-major layout.
__global__ __launch_bounds__(256) void tick_update(
    const float* __restrict__ G,
    const float* __restrict__ b_ih0, const float* __restrict__ b_hh0,
    const float* __restrict__ b_ih1, const float* __restrict__ b_hh1,
    const float* __restrict__ g_ih0, const float* __restrict__ be_ih0,
    const float* __restrict__ g_hh0, const float* __restrict__ be_hh0,
    const float* __restrict__ g_ho0, const float* __restrict__ be_ho0,
    const float* __restrict__ g_ih1, const float* __restrict__ be_ih1,
    const float* __restrict__ g_hh1, const float* __restrict__ be_hh1,
    const float* __restrict__ g_ho1, const float* __restrict__ be_ho1,
    float* __restrict__ h0, float* __restrict__ c0,
    float* __restrict__ h1, float* __restrict__ c1,
    half_t* __restrict__ h0fh, half_t* __restrict__ h0fl,
    half_t* __restrict__ h1fh, half_t* __restrict__ h1fl, int t)
{
  const int layer = blockIdx.x >> 9;
  const int b = blockIdx.x & 511;
  if (layer==0 && t>=SEQ) return;   // layer0 active ticks 0..199
  if (layer==1 && t==0)   return;   // layer1 active ticks 1..200 (processes step t-1)

  const float *GA,*GB,*bA,*bB,*gA,*beA,*gB,*beB,*gH,*bH;
  float *cs,*hs; half_t *hfx,*lfx;
  const size_t rb = (size_t)b*GW;
  if (layer==0){
    GA = G + rb;
    GB = G + (size_t)1*BATCH*GW + rb;
    bA=b_ih0; bB=b_hh0;
    gA=g_ih0; beA=be_ih0; gB=g_hh0; beB=be_hh0; gH=g_ho0; bH=be_ho0;
    cs = c0 + b*HID; hs = h0 + b*HID; hfx = h0fh; lfx = h0fl;
  } else {
    GA = G + (size_t)2*BATCH*GW + rb;
    GB = G + (size_t)3*BATCH*GW + rb;
    bA=b_ih1; bB=b_hh1;
    gA=g_ih1; beA=be_ih1; gB=g_hh1; beB=be_hh1; gH=g_ho1; bH=be_ho1;
    cs = c1 + b*HID; hs = h1 + b*HID; hfx = h1fh; lfx = h1fl;
  }

  const int tid = threadIdx.x;
  __shared__ float red[16];
  __shared__ __align__(16) float GS[2*GW];     // 16 KB: A-part then B-part
  __shared__ float su[HID];
  __shared__ float so[HID];

  // Pass 1 (float4): bias add, stage into LDS, LN stats for both vectors
  float sa=0, ssa=0, sb=0, ssb=0;
  for (int i=tid*4; i<GW; i+=1024){
    f32x4 va = *(const f32x4*)(GA+i);
    va += *(const f32x4*)(bA+i);
    *(f32x4*)(GS+i) = va;
    f32x4 vb = *(const f32x4*)(GB+i);
    vb += *(const f32x4*)(bB+i);
    *(f32x4*)(GS+GW+i) = vb;
    #pragma unroll
    for (int q=0;q<4;q++){
      sa += va[q]; ssa += va[q]*va[q];
      sb += vb[q]; ssb += vb[q]*vb[q];
    }
  }
  block_reduce4(sa,ssa,sb,ssb,red);   // internal __syncthreads covers GS visibility
  const float ma = sa*(1.0f/GW);
  const float ra = rsqrtf(ssa*(1.0f/GW) - ma*ma + EPS);
  const float mb = sb*(1.0f/GW);
  const float rb_ = rsqrtf(ssb*(1.0f/GW) - mb*mb + EPS);

  // Pass 2: gates (i,f,g,o split), cell update, tanh(c) stats
  float s_u=0, s_uu=0;
  for (int j=tid;j<HID;j+=256){
    float iv = ((GS[j      ]-ma)*ra*gA[j      ]+beA[j      ]) + ((GS[GW+j      ]-mb)*rb_*gB[j      ]+beB[j      ]);
    float fv = ((GS[j+  HID]-ma)*ra*gA[j+  HID]+beA[j+  HID]) + ((GS[GW+j+  HID]-mb)*rb_*gB[j+  HID]+beB[j+  HID]);
    float gv = ((GS[j+2*HID]-ma)*ra*gA[j+2*HID]+beA[j+2*HID]) + ((GS[GW+j+2*HID]-mb)*rb_*gB[j+2*HID]+beB[j+2*HID]);
    float ov = ((GS[j+3*HID]-ma)*ra*gA[j+3*HID]+beA[j+3*HID]) + ((GS[GW+j+3*HID]-mb)*rb_*gB[j+3*HID]+beB[j+3*HID]);
    float cn = sigf(fv)*cs[j] + sigf(iv)*tanhf(gv);
    cs[j] = cn;
    float u = tanhf(cn);
    su[j] = u; so[j] = sigf(ov);
    s_u += u; s_uu += u*u;
  }
  float d3=0,d4=0;
  block_reduce4(s_u,s_uu,d3,d4,red);
  const float mu_u = s_u*(1.0f/HID);
  const float ru   = rsqrtf(s_uu*(1.0f/HID) - mu_u*mu_u + EPS);

  // Pass 3: h = sigmoid(o) * LN(tanh(c)); fp32 linear + fp16 hi/lo in
  // fragment layout: idx = ((b>>5)*32 + (j>>4))*512 + ((b&31)+((j>>3)&1)*32)*8 + (j&7)
  const size_t fbase = ((size_t)(b>>5)*32)*512 + (size_t)(b&31)*8;
  for (int j=tid;j<HID;j+=256){
    float v = so[j] * ((su[j]-mu_u)*ru*gH[j] + bH[j]);
    hs[j] = v;
    half_t hv = (half_t)v;
    half_t lv = (half_t)(v - (float)hv);
    const size_t fi = fbase + (size_t)(j>>4)*512 + (size_t)((j>>3)&1)*256 + (j&7);
    hfx[fi] = hv;
    lfx[fi] = lv;
  }
}

// Dense head: 512 -> 128 -> 64 -> 32 -> 1, one block per batch row
__global__ __launch_bounds__(256) void head_kernel(
    const float* __restrict__ h1,
    const float* __restrict__ Wd1, const float* __restrict__ bd1,
    const float* __restrict__ Wd2, const float* __restrict__ bd2,
    const float* __restrict__ Wd3, const float* __restrict__ bd3,
    const float* __restrict__ Wd4, const float* __restrict__ bd4,
    float* __restrict__ out)
{
  const int b = blockIdx.x;
  __shared__ float hv[HID];
  __shared__ float z1[128];
  __shared__ float z2[64];
  __shared__ float z3[32];
  const int tid = threadIdx.x;
  for (int i=tid;i<HID;i+=256) hv[i]=h1[(size_t)b*HID+i];
  __syncthreads();
  if (tid<128){
    float acc=bd1[tid]; const float* w=Wd1+(size_t)tid*512;
    for(int k=0;k<512;k++) acc+=hv[k]*w[k];
    z1[tid]=fmaxf(acc,0.f);
  }
  __syncthreads();
  if (tid<64){
    float acc=bd2[tid]; const float* w=Wd2+(size_t)tid*128;
    for(int k=0;k<128;k++) acc+=z1[k]*w[k];
    z2[tid]=fmaxf(acc,0.f);
  }
  __syncthreads();
  if (tid<32){
    float acc=bd3[tid]; const float* w=Wd3+(size_t)tid*64;
    for(int k=0;k<64;k++) acc+=z2[k]*w[k];
    z3[tid]=fmaxf(acc,0.f);
  }
  __syncthreads();
  if (tid==0){
    float acc=bd4[0];
    for(int k=0;k<32;k++) acc+=z3[k]*Wd4[k];
    out[b]=acc;
  }
}

extern "C" void kernel_launch(void* const* d_in, const int* in_sizes, int n_in,
                              void* d_out, int out_size, void* d_ws, size_t ws_size,
                              hipStream_t stream) {
  const float* x      = (const float*)d_in[0];
  const float* ln1_g  = (const float*)d_in[1];
  const float* ln1_b  = (const float*)d_in[2];
  const float* W_ih0  = (const float*)d_in[3];
  const float* b_ih0  = (const float*)d_in[4];
  const float* W_hh0  = (const float*)d_in[5];
  const float* b_hh0  = (const float*)d_in[6];
  const float* g_ih0  = (const float*)d_in[7];
  const float* be_ih0 = (const float*)d_in[8];
  const float* g_hh0  = (const float*)d_in[9];
  const float* be_hh0 = (const float*)d_in[10];
  const float* g_ho0  = (const float*)d_in[11];
  const float* be_ho0 = (const float*)d_in[12];
  const float* W_ih1  = (const float*)d_in[13];
  const float* b_ih1  = (const float*)d_in[14];
  const float* W_hh1  = (const float*)d_in[15];
  const float* b_hh1  = (const float*)d_in[16];
  const float* g_ih1  = (const float*)d_in[17];
  const float* be_ih1 = (const float*)d_in[18];
  const float* g_hh1  = (const float*)d_in[19];
  const float* be_hh1 = (const float*)d_in[20];
  const float* g_ho1  = (const float*)d_in[21];
  const float* be_ho1 = (const float*)d_in[22];
  const float* Wd1    = (const float*)d_in[23];
  const float* bd1    = (const float*)d_in[24];
  const float* Wd2    = (const float*)d_in[25];
  const float* bd2    = (const float*)d_in[26];
  const float* Wd3    = (const float*)d_in[27];
  const float* bd3    = (const float*)d_in[28];
  const float* Wd4    = (const float*)d_in[29];
  const float* bd4    = (const float*)d_in[30];
  float* out = (float*)d_out;

  // ---- workspace layout ----
  float* ws = (float*)d_ws;
  float* G  = ws;                                   // 4*512*2048 f32 = 16 MB
  float* h0 = G  + NREG*(size_t)BATCH*GW;           // fp32 state block (zeroed)
  float* c0 = h0 + (size_t)BATCH*HID;
  float* h1 = c0 + (size_t)BATCH*HID;
  float* c1 = h1 + (size_t)BATCH*HID;
  half_t* h0fh = (half_t*)(c1 + (size_t)BATCH*HID); // fp16 frag splits (zeroed)
  half_t* h0fl = h0fh + (size_t)BATCH*HID;
  half_t* h1fh = h0fl + (size_t)BATCH*HID;
  half_t* h1fl = h1fh + (size_t)BATCH*HID;
  float* mu = (float*)(h1fl + (size_t)BATCH*HID);   // 512
  float* rs = mu + BATCH;                           // 512
  half_t* Wh = (half_t*)(rs + BATCH);               // WTOT halves (packed)
  half_t* Wl = Wh + (size_t)WTOT;                   // WTOT halves (packed)

  // zero h0,c0,h1,c1 (fp32) + 4 frag planes (fp16) in one contiguous memset
  hipMemsetAsync(h0, 0, 4*(size_t)BATCH*HID*4 + 4*(size_t)BATCH*HID*2, stream);

  ln1_stats<<<BATCH, 256, 0, stream>>>(x, mu, rs);
  wsplit<<<(WTOT+255)/256, 256, 0, stream>>>(W_ih0, W_hh0, W_ih1, W_hh1, Wh, Wl);

  dim3 mgrid(16, 8, NREG);
  for (int t = 0; t <= SEQ; ++t) {
    tick_mm32<<<mgrid, 256, 0, stream>>>(x, ln1_g, ln1_b, mu, rs,
        h0fh, h0fl, h1fh, h1fl, Wh, Wl, G, t);
    tick_update<<<dim3(1024), 256, 0, stream>>>(G,
        b_ih0, b_hh0, b_ih1, b_hh1,
        g_ih0, be_ih0, g_hh0, be_hh0, g_ho0, be_ho0,
        g_ih1, be_ih1, g_hh1, be_hh1, g_ho1, be_ho1,
        h0, c0, h1, c1, h0fh, h0fl, h1fh, h1fl, t);
  }
  head_kernel<<<BATCH, 256, 0, stream>>>(h1, Wd1, bd1, Wd2, bd2, Wd3, bd3, Wd4, bd4, out);
}

// Round 5
// 5676.912 us; speedup vs baseline: 10.2072x; 1.0618x over previous
//
#include <hip/hip_runtime.h>
#include <math.h>

#define BATCH 512
#define SEQ   200
#define DIN   64
#define HID   512
#define GW    2048   // 4*HID
#define EPS   1e-5f
#define NREG  4      // G regions: ih0 | hh0 | ih1 | hh1

typedef _Float16 half_t;
typedef half_t half8 __attribute__((ext_vector_type(8)));
typedef float  f32x4  __attribute__((ext_vector_type(4)));
typedef float  f32x16 __attribute__((ext_vector_type(16)));

#define WN0 (2048*64)     // W_ih0 elems
#define WN1 (2048*512)    // W_hh0 / W_ih1 / W_hh1 elems
#define WTOT (WN0 + 3*WN1)
#define XFRAG ((size_t)SEQ*16*4*512)   // per-plane xsplit elems (frag-major)

__device__ __forceinline__ float sigf(float x){ return 1.0f/(1.0f+expf(-x)); }

// Reduce 4 values across a 256-thread block. red must be float[16] shared.
__device__ __forceinline__ void block_reduce4(float&a,float&b,float&c,float&d,float* red){
  #pragma unroll
  for(int o=32;o;o>>=1){
    a+=__shfl_down(a,o); b+=__shfl_down(b,o);
    c+=__shfl_down(c,o); d+=__shfl_down(d,o);
  }
  const int lane = threadIdx.x & 63, wid = threadIdx.x>>6;
  if(lane==0){ red[wid*4+0]=a; red[wid*4+1]=b; red[wid*4+2]=c; red[wid*4+3]=d; }
  __syncthreads();
  a = red[0]+red[4]+red[8]+red[12];
  b = red[1]+red[5]+red[9]+red[13];
  c = red[2]+red[6]+red[10]+red[14];
  d = red[3]+red[7]+red[11]+red[15];
  __syncthreads();
}

// Per-batch-row stats for ln1 (joint LayerNorm over (S,D) = 12800 elems)
__global__ __launch_bounds__(256) void ln1_stats(const float* __restrict__ x,
                                                 float* __restrict__ mu,
                                                 float* __restrict__ rs){
  const int b = blockIdx.x;
  const float* xb = x + (size_t)b*SEQ*DIN;
  float s=0, ss=0, d=0, e=0;
  for (int i=threadIdx.x; i<SEQ*DIN; i+=256){ float v=xb[i]; s+=v; ss+=v*v; }
  __shared__ float red[16];
  block_reduce4(s,ss,d,e,red);
  if (threadIdx.x==0){
    float m = s*(1.0f/(SEQ*DIN));
    mu[b] = m;
    rs[b] = rsqrtf(ss*(1.0f/(SEQ*DIN)) - m*m + EPS);
  }
}

// Split the 4 weight matrices into fp16 hi/lo in FRAGMENT-MAJOR packed layout.
//   idx = ((p*C + c)*4 + nf*2 + ks)*512 + l*8 + j
//   n = p*64 + nf*32 + (l&31);  k = c*32 + ks*16 + (l>>5)*8 + j
__global__ __launch_bounds__(256) void wsplit(
    const float* __restrict__ W0, const float* __restrict__ W1,
    const float* __restrict__ W2, const float* __restrict__ W3,
    half_t* __restrict__ Wh, half_t* __restrict__ Wl)
{
  int i = blockIdx.x*256 + threadIdx.x;
  if (i >= WTOT) return;
  const float* src; int off, Kd;
  if (i < WN0){ src=W0; off=i; Kd=DIN; }
  else {
    int r = (i-WN0)/WN1; off = (i-WN0) - r*WN1; Kd=HID;
    src = (r==0)?W1:((r==1)?W2:W3);
  }
  const int C = Kd>>5;            // 2 or 16 (pow2)
  int j  = off & 7;
  int l  = (off>>3) & 63;
  int ks = (off>>9) & 1;
  int nf = (off>>10) & 1;
  int pc = off>>11;
  int c  = pc & (C-1);
  int p  = pc >> (Kd==DIN ? 1 : 4);
  int n  = p*64 + nf*32 + (l&31);
  int k  = c*32 + ks*16 + (l>>5)*8 + j;
  float v = src[(size_t)n*Kd + k];
  half_t h = (half_t)v;
  Wh[i] = h;
  Wl[i] = (half_t)(v - (float)h);
}

// Precompute ln1(x) fp16 hi/lo splits for ALL t in MFMA-A-fragment layout:
//   idx = ((t*16 + mch)*4 + c)*512 + l*8 + j
//   b = mch*32 + (l&31);  k = c*16 + (l>>5)*8 + j
__global__ __launch_bounds__(256) void xprep(
    const float* __restrict__ x, const float* __restrict__ g1, const float* __restrict__ b1,
    const float* __restrict__ mu, const float* __restrict__ rs,
    half_t* __restrict__ xh, half_t* __restrict__ xl)
{
  size_t i = (size_t)blockIdx.x*256 + threadIdx.x;
  if (i >= XFRAG) return;
  int j   = (int)(i & 7);
  int l   = (int)((i>>3) & 63);
  int c   = (int)((i>>9) & 3);
  int mch = (int)((i>>11) & 15);
  int t   = (int)(i>>15);
  int b   = mch*32 + (l&31);
  int k   = c*16 + ((l>>5)<<3) + j;
  float v = (x[(size_t)b*(SEQ*DIN) + t*DIN + k] - mu[b]) * rs[b]
            * g1[t*DIN+k] + b1[t*DIN+k];
  half_t h = (half_t)v;
  xh[i] = h;
  xl[i] = (half_t)(v - (float)h);
}

// One tick: gate pre-activation GEMMs via split-fp16 32x32x16 MFMA.
// Wave tile 64m x 64n (2 m-chunks x 2 n-frags, 12 MFMA / 8KB loads).
// Block = 4 waves sharing the SAME 64 A-rows (L1 reuse), different 64-col panels.
// grid = (8 n, 8 m, 4 regions) = 256 blocks = 1/CU. All loads wave-uniform+lane*16B.
// regions: 0: G_ih0 = ln1x(t) @ W_ih0^T (K=64, A from xsplit)
//          1: G_hh0 = h0 @ W_hh0^T   2: G_ih1 = h0 @ W_ih1^T   3: G_hh1 = h1 @ W_hh1^T
__global__ __launch_bounds__(256, 1) void tick_mm64(
    const half_t* __restrict__ xh, const half_t* __restrict__ xl,
    const half_t* __restrict__ h0fh, const half_t* __restrict__ h0fl,
    const half_t* __restrict__ h1fh, const half_t* __restrict__ h1fl,
    const half_t* __restrict__ Wh, const half_t* __restrict__ Wl,
    float* __restrict__ G, int t)
{
  const int z    = blockIdx.z;           // region 0..3
  const int tid  = threadIdx.x;
  const int lane = tid & 63;
  const int w    = tid >> 6;
  const int ln31 = lane & 31;

  const int mch0 = blockIdx.y*2;         // two 32-row m-chunks (64 rows)
  const int p    = blockIdx.x*4 + w;     // 64-col weight panel (0..31)
  const int wn0  = p*64;

  const half_t* Bh = Wh + WN0; const half_t* Bl = Wl + WN0;
  int Kd = HID;
  if (z==0){ Bh=Wh; Bl=Wl; Kd=DIN; }
  else if (z==2){ Bh=Wh+WN0+WN1; Bl=Wl+WN0+WN1; }
  else if (z==3){ Bh=Wh+WN0+2*WN1; Bl=Wl+WN0+2*WN1; }

  const int C32 = Kd >> 5;
  const int C16 = Kd >> 4;

  // wave-uniform bases (+ lane*8 elems = lane*16B)
  const half_t* Bph = Bh + (size_t)p*C32*2048 + lane*8;
  const half_t* Bpl = Bl + (size_t)p*C32*2048 + lane*8;

  const int tq = (t < SEQ) ? t : (SEQ-1);   // t==200 region0 result unused
  const half_t *Aph0,*Apl0,*Aph1,*Apl1;     // per-m-chunk frag bases, stride 512/chunk
  if (z==0){
    const size_t xb = ((size_t)tq*16 + mch0)*2048 + lane*8;
    Aph0 = xh + xb; Aph1 = xh + xb + 2048;
    Apl0 = xl + xb; Apl1 = xl + xb + 2048;
  } else {
    const half_t* FAh = (z==3) ? h1fh : h0fh;
    const half_t* FAl = (z==3) ? h1fl : h0fl;
    const size_t ab = (size_t)mch0*16384 + lane*8;   // mch * 32chunks * 512
    Aph0 = FAh + ab; Aph1 = FAh + ab + 16384;
    Apl0 = FAl + ab; Apl1 = FAl + ab + 16384;
  }

  f32x16 acc00 = {0.f,0.f,0.f,0.f,0.f,0.f,0.f,0.f,0.f,0.f,0.f,0.f,0.f,0.f,0.f,0.f};
  f32x16 acc01 = acc00, acc10 = acc00, acc11 = acc00;

  struct F { half8 ah0,al0,ah1,al1,bh0,bh1,bl0,bl1; };
  auto loadF = [&](int c)->F{
    F f;
    const size_t ao = (size_t)c*512;
    f.ah0 = *(const half8*)(Aph0 + ao);
    f.al0 = *(const half8*)(Apl0 + ao);
    f.ah1 = *(const half8*)(Aph1 + ao);
    f.al1 = *(const half8*)(Apl1 + ao);
    const size_t bo = (size_t)(c>>1)*2048 + (size_t)(c&1)*512;
    f.bh0 = *(const half8*)(Bph + bo);
    f.bh1 = *(const half8*)(Bph + bo + 1024);
    f.bl0 = *(const half8*)(Bpl + bo);
    f.bl1 = *(const half8*)(Bpl + bo + 1024);
    return f;
  };
  auto mmstep = [&](const F& f){
    acc00 = __builtin_amdgcn_mfma_f32_32x32x16_f16(f.ah0, f.bh0, acc00, 0,0,0);
    acc01 = __builtin_amdgcn_mfma_f32_32x32x16_f16(f.ah0, f.bh1, acc01, 0,0,0);
    acc10 = __builtin_amdgcn_mfma_f32_32x32x16_f16(f.ah1, f.bh0, acc10, 0,0,0);
    acc11 = __builtin_amdgcn_mfma_f32_32x32x16_f16(f.ah1, f.bh1, acc11, 0,0,0);
    acc00 = __builtin_amdgcn_mfma_f32_32x32x16_f16(f.al0, f.bh0, acc00, 0,0,0);
    acc01 = __builtin_amdgcn_mfma_f32_32x32x16_f16(f.al0, f.bh1, acc01, 0,0,0);
    acc10 = __builtin_amdgcn_mfma_f32_32x32x16_f16(f.al1, f.bh0, acc10, 0,0,0);
    acc11 = __builtin_amdgcn_mfma_f32_32x32x16_f16(f.al1, f.bh1, acc11, 0,0,0);
    acc00 = __builtin_amdgcn_mfma_f32_32x32x16_f16(f.ah0, f.bl0, acc00, 0,0,0);
    acc01 = __builtin_amdgcn_mfma_f32_32x32x16_f16(f.ah0, f.bl1, acc01, 0,0,0);
    acc10 = __builtin_amdgcn_mfma_f32_32x32x16_f16(f.ah1, f.bl0, acc10, 0,0,0);
    acc11 = __builtin_amdgcn_mfma_f32_32x32x16_f16(f.ah1, f.bl1, acc11, 0,0,0);
  };

  // pipeline: loads issued 2..3 chunks ahead of their mmstep (~24 MFMA of cover)
  F f0 = loadF(0);
  F f1 = loadF(1);
  for (int c=0; c<C16; c+=2){
    F f2, f3;
    if (c+2 < C16){ f2 = loadF(c+2); f3 = loadF(c+3); }
    mmstep(f0);
    mmstep(f1);
    f0 = f2; f1 = f3;
  }

  // C/D 32x32: col = lane&31, row = (reg&3)+8*(reg>>2)+4*(lane>>5)
  // Nontemporal: G streams to L3/HBM; keeps per-XCD L2 for weights + h-state.
  float* Gr = G + (size_t)z*BATCH*GW;
  const int rbase = (lane>>5)<<2;
  #pragma unroll
  for (int reg=0; reg<16; reg++){
    const int row = (reg&3) + ((reg>>2)<<3) + rbase;
    const int m0 = mch0*32 + row;
    const int m1 = m0 + 32;
    __builtin_nontemporal_store(acc00[reg], &Gr[(size_t)m0*GW + wn0 + ln31]);
    __builtin_nontemporal_store(acc01[reg], &Gr[(size_t)m0*GW + wn0 + 32 + ln31]);
    __builtin_nontemporal_store(acc10[reg], &Gr[(size_t)m1*GW + wn0 + ln31]);
    __builtin_nontemporal_store(acc11[reg], &Gr[(size_t)m1*GW + wn0 + 32 + ln31]);
  }
}

// One block per (layer, batch-row): bias + gate LN + cell update + h LN.
// Emits h fp32 (linear) and fp16 hi/lo splits in MFMA-fragment-major layout.
__global__ __launch_bounds__(256) void tick_update(
    const float* __restrict__ G,
    const float* __restrict__ b_ih0, const float* __restrict__ b_hh0,
    const float* __restrict__ b_ih1, const float* __restrict__ b_hh1,
    const float* __restrict__ g_ih0, const float* __restrict__ be_ih0,
    const float* __restrict__ g_hh0, const float* __restrict__ be_hh0,
    const float* __restrict__ g_ho0, const float* __restrict__ be_ho0,
    const float* __restrict__ g_ih1, const float* __restrict__ be_ih1,
    const float* __restrict__ g_hh1, const float* __restrict__ be_hh1,
    const float* __restrict__ g_ho1, const float* __restrict__ be_ho1,
    float* __restrict__ h0, float* __restrict__ c0,
    float* __restrict__ h1, float* __restrict__ c1,
    half_t* __restrict__ h0fh, half_t* __restrict__ h0fl,
    half_t* __restrict__ h1fh, half_t* __restrict__ h1fl, int t)
{
  const int layer = blockIdx.x >> 9;
  const int b = blockIdx.x & 511;
  if (layer==0 && t>=SEQ) return;   // layer0 active ticks 0..199
  if (layer==1 && t==0)   return;   // layer1 active ticks 1..200 (processes step t-1)

  const float *GA,*GB,*bA,*bB,*gA,*beA,*gB,*beB,*gH,*bH;
  float *cs,*hs; half_t *hfx,*lfx;
  const size_t rb = (size_t)b*GW;
  if (layer==0){
    GA = G + rb;
    GB = G + (size_t)1*BATCH*GW + rb;
    bA=b_ih0; bB=b_hh0;
    gA=g_ih0; beA=be_ih0; gB=g_hh0; beB=be_hh0; gH=g_ho0; bH=be_ho0;
    cs = c0 + b*HID; hs = h0 + b*HID; hfx = h0fh; lfx = h0fl;
  } else {
    GA = G + (size_t)2*BATCH*GW + rb;
    GB = G + (size_t)3*BATCH*GW + rb;
    bA=b_ih1; bB=b_hh1;
    gA=g_ih1; beA=be_ih1; gB=g_hh1; beB=be_hh1; gH=g_ho1; bH=be_ho1;
    cs = c1 + b*HID; hs = h1 + b*HID; hfx = h1fh; lfx = h1fl;
  }

  const int tid = threadIdx.x;
  __shared__ float red[16];
  __shared__ __align__(16) float GS[2*GW];     // 16 KB: A-part then B-part
  __shared__ float su[HID];
  __shared__ float so[HID];

  // Pass 1 (float4): bias add, stage into LDS, LN stats for both vectors
  float sa=0, ssa=0, sb=0, ssb=0;
  for (int i=tid*4; i<GW; i+=1024){
    f32x4 va = *(const f32x4*)(GA+i);
    va += *(const f32x4*)(bA+i);
    *(f32x4*)(GS+i) = va;
    f32x4 vb = *(const f32x4*)(GB+i);
    vb += *(const f32x4*)(bB+i);
    *(f32x4*)(GS+GW+i) = vb;
    #pragma unroll
    for (int q=0;q<4;q++){
      sa += va[q]; ssa += va[q]*va[q];
      sb += vb[q]; ssb += vb[q]*vb[q];
    }
  }
  block_reduce4(sa,ssa,sb,ssb,red);   // internal __syncthreads covers GS visibility
  const float ma = sa*(1.0f/GW);
  const float ra = rsqrtf(ssa*(1.0f/GW) - ma*ma + EPS);
  const float mb = sb*(1.0f/GW);
  const float rb_ = rsqrtf(ssb*(1.0f/GW) - mb*mb + EPS);

  // Pass 2: gates (i,f,g,o split), cell update, tanh(c) stats
  float s_u=0, s_uu=0;
  for (int j=tid;j<HID;j+=256){
    float iv = ((GS[j      ]-ma)*ra*gA[j      ]+beA[j      ]) + ((GS[GW+j      ]-mb)*rb_*gB[j      ]+beB[j      ]);
    float fv = ((GS[j+  HID]-ma)*ra*gA[j+  HID]+beA[j+  HID]) + ((GS[GW+j+  HID]-mb)*rb_*gB[j+  HID]+beB[j+  HID]);
    float gv = ((GS[j+2*HID]-ma)*ra*gA[j+2*HID]+beA[j+2*HID]) + ((GS[GW+j+2*HID]-mb)*rb_*gB[j+2*HID]+beB[j+2*HID]);
    float ov = ((GS[j+3*HID]-ma)*ra*gA[j+3*HID]+beA[j+3*HID]) + ((GS[GW+j+3*HID]-mb)*rb_*gB[j+3*HID]+beB[j+3*HID]);
    float cn = sigf(fv)*cs[j] + sigf(iv)*tanhf(gv);
    cs[j] = cn;
    float u = tanhf(cn);
    su[j] = u; so[j] = sigf(ov);
    s_u += u; s_uu += u*u;
  }
  float d3=0,d4=0;
  block_reduce4(s_u,s_uu,d3,d4,red);
  const float mu_u = s_u*(1.0f/HID);
  const float ru   = rsqrtf(s_uu*(1.0f/HID) - mu_u*mu_u + EPS);

  // Pass 3: h = sigmoid(o) * LN(tanh(c)); fp32 linear + fp16 hi/lo in
  // fragment layout: idx = ((b>>5)*32 + (j>>4))*512 + ((b&31)+((j>>3)&1)*32)*8 + (j&7)
  const size_t fbase = ((size_t)(b>>5)*32)*512 + (size_t)(b&31)*8;
  for (int j=tid;j<HID;j+=256){
    float v = so[j] * ((su[j]-mu_u)*ru*gH[j] + bH[j]);
    hs[j] = v;
    half_t hv = (half_t)v;
    half_t lv = (half_t)(v - (float)hv);
    const size_t fi = fbase + (size_t)(j>>4)*512 + (size_t)((j>>3)&1)*256 + (j&7);
    hfx[fi] = hv;
    lfx[fi] = lv;
  }
}

// Dense head: 512 -> 128 -> 64 -> 32 -> 1, one block per batch row
__global__ __launch_bounds__(256) void head_kernel(
    const float* __restrict__ h1,
    const float* __restrict__ Wd1, const float* __restrict__ bd1,
    const float* __restrict__ Wd2, const float* __restrict__ bd2,
    const float* __restrict__ Wd3, const float* __restrict__ bd3,
    const float* __restrict__ Wd4, const float* __restrict__ bd4,
    float* __restrict__ out)
{
  const int b = blockIdx.x;
  __shared__ float hv[HID];
  __shared__ float z1[128];
  __shared__ float z2[64];
  __shared__ float z3[32];
  const int tid = threadIdx.x;
  for (int i=tid;i<HID;i+=256) hv[i]=h1[(size_t)b*HID+i];
  __syncthreads();
  if (tid<128){
    float acc=bd1[tid]; const float* w=Wd1+(size_t)tid*512;
    for(int k=0;k<512;k++) acc+=hv[k]*w[k];
    z1[tid]=fmaxf(acc,0.f);
  }
  __syncthreads();
  if (tid<64){
    float acc=bd2[tid]; const float* w=Wd2+(size_t)tid*128;
    for(int k=0;k<128;k++) acc+=z1[k]*w[k];
    z2[tid]=fmaxf(acc,0.f);
  }
  __syncthreads();
  if (tid<32){
    float acc=bd3[tid]; const float* w=Wd3+(size_t)tid*64;
    for(int k=0;k<64;k++) acc+=z2[k]*w[k];
    z3[tid]=fmaxf(acc,0.f);
  }
  __syncthreads();
  if (tid==0){
    float acc=bd4[0];
    for(int k=0;k<32;k++) acc+=z3[k]*Wd4[k];
    out[b]=acc;
  }
}

extern "C" void kernel_launch(void* const* d_in, const int* in_sizes, int n_in,
                              void* d_out, int out_size, void* d_ws, size_t ws_size,
                              hipStream_t stream) {
  const float* x      = (const float*)d_in[0];
  const float* ln1_g  = (const float*)d_in[1];
  const float* ln1_b  = (const float*)d_in[2];
  const float* W_ih0  = (const float*)d_in[3];
  const float* b_ih0  = (const float*)d_in[4];
  const float* W_hh0  = (const float*)d_in[5];
  const float* b_hh0  = (const float*)d_in[6];
  const float* g_ih0  = (const float*)d_in[7];
  const float* be_ih0 = (const float*)d_in[8];
  const float* g_hh0  = (const float*)d_in[9];
  const float* be_hh0 = (const float*)d_in[10];
  const float* g_ho0  = (const float*)d_in[11];
  const float* be_ho0 = (const float*)d_in[12];
  const float* W_ih1  = (const float*)d_in[13];
  const float* b_ih1  = (const float*)d_in[14];
  const float* W_hh1  = (const float*)d_in[15];
  const float* b_hh1  = (const float*)d_in[16];
  const float* g_ih1  = (const float*)d_in[17];
  const float* be_ih1 = (const float*)d_in[18];
  const float* g_hh1  = (const float*)d_in[19];
  const float* be_hh1 = (const float*)d_in[20];
  const float* g_ho1  = (const float*)d_in[21];
  const float* be_ho1 = (const float*)d_in[22];
  const float* Wd1    = (const float*)d_in[23];
  const float* bd1    = (const float*)d_in[24];
  const float* Wd2    = (const float*)d_in[25];
  const float* bd2    = (const float*)d_in[26];
  const float* Wd3    = (const float*)d_in[27];
  const float* bd3    = (const float*)d_in[28];
  const float* Wd4    = (const float*)d_in[29];
  const float* bd4    = (const float*)d_in[30];
  float* out = (float*)d_out;

  // ---- workspace layout ----
  float* ws = (float*)d_ws;
  float* G  = ws;                                   // 4*512*2048 f32 = 16 MB
  float* h0 = G  + NREG*(size_t)BATCH*GW;           // fp32 state block (zeroed)
  float* c0 = h0 + (size_t)BATCH*HID;
  float* h1 = c0 + (size_t)BATCH*HID;
  float* c1 = h1 + (size_t)BATCH*HID;
  half_t* h0fh = (half_t*)(c1 + (size_t)BATCH*HID); // fp16 frag splits (zeroed)
  half_t* h0fl = h0fh + (size_t)BATCH*HID;
  half_t* h1fh = h0fl + (size_t)BATCH*HID;
  half_t* h1fl = h1fh + (size_t)BATCH*HID;
  float* mu = (float*)(h1fl + (size_t)BATCH*HID);   // 512
  float* rs = mu + BATCH;                           // 512
  half_t* Wh = (half_t*)(rs + BATCH);               // WTOT halves (packed)
  half_t* Wl = Wh + (size_t)WTOT;                   // WTOT halves (packed)
  half_t* xh = Wl + (size_t)WTOT;                   // XFRAG halves (frag-major)
  half_t* xl = xh + XFRAG;

  // zero h0,c0,h1,c1 (fp32) + 4 frag planes (fp16) in one contiguous memset
  hipMemsetAsync(h0, 0, 4*(size_t)BATCH*HID*4 + 4*(size_t)BATCH*HID*2, stream);

  ln1_stats<<<BATCH, 256, 0, stream>>>(x, mu, rs);
  wsplit<<<(WTOT+255)/256, 256, 0, stream>>>(W_ih0, W_hh0, W_ih1, W_hh1, Wh, Wl);
  xprep<<<(int)((XFRAG+255)/256), 256, 0, stream>>>(x, ln1_g, ln1_b, mu, rs, xh, xl);

  dim3 mgrid(8, 8, NREG);
  for (int t = 0; t <= SEQ; ++t) {
    tick_mm64<<<mgrid, 256, 0, stream>>>(xh, xl,
        h0fh, h0fl, h1fh, h1fl, Wh, Wl, G, t);
    tick_update<<<dim3(1024), 256, 0, stream>>>(G,
        b_ih0, b_hh0, b_ih1, b_hh1,
        g_ih0, be_ih0, g_hh0, be_hh0, g_ho0, be_ho0,
        g_ih1, be_ih1, g_hh1, be_hh1, g_ho1, be_ho1,
        h0, c0, h1, c1, h0fh, h0fl, h1fh, h1fl, t);
  }
  head_kernel<<<BATCH, 256, 0, stream>>>(h1, Wd1, bd1, Wd2, bd2, Wd3, bd3, Wd4, bd4, out);
}